// Round 7
// baseline (66.524 us; speedup 1.0000x reference)
//
#include <hip/hip_runtime.h>
#include <stdint.h>
#include <stddef.h>

// MultiTaskTrunkNetwork: 3x (Linear+Tanh) [89->64->64->64] + per-task head [64->8]
// Round 7: kill the staging stage. Fully wave-private, ZERO barriers.
//   - layer-0 B-frags loaded directly global->VGPR (6x32B/lane), f16 convert in-reg
//   - no x LDS tile: LDS = h band only [4][32][76] f16 = 19.5 KB
//   - frag-ordered weights (r5) + coalesced-chunk head with shuffle reduce (r6)
//   - task + hB prefetched at kernel top

typedef _Float16 half8 __attribute__((ext_vector_type(8)));
typedef _Float16 half4 __attribute__((ext_vector_type(4)));
typedef _Float16 half2v __attribute__((ext_vector_type(2)));
typedef float    f32x4 __attribute__((ext_vector_type(4)));

constexpr int BN = 262144, INF = 89, HID = 64, OUTF = 8, NTASK = 50;
constexpr int NTHR = 256;     // 4 waves
constexpr int ROWS = 128;     // batch rows per block (32 per wave)
constexpr int HP   = 76;      // LDS h pitch in f16 (152 B -> bank stride 38 dwords)

// d_ws layout (bytes) — fragment-ordered weights
constexpr int W0F_OFF = 0;        // [3kk][4ft][64lane][8] f16 = 12288 B (k>=89 zero)
constexpr int W1F_OFF = 12288;    // [2kk][4ft][64lane][8] f16 = 8192 B
constexpr int W2F_OFF = 20480;    // [2kk][4ft][64lane][8] f16 = 8192 B
constexpr int HWT_OFF = 28672;    // [50][8][64] f16 (transposed head weights)

__device__ __forceinline__ float fast_tanh(float v) {
    float e = __expf(2.0f * v);
    return 1.0f - 2.0f * __builtin_amdgcn_rcpf(e + 1.0f);
}

__device__ __forceinline__ float dot2acc(half2v a, half2v b, float c) {
#if __has_builtin(__builtin_amdgcn_fdot2)
    return __builtin_amdgcn_fdot2(a, b, c, false);
#else
    return fmaf((float)a[0], (float)b[0], fmaf((float)a[1], (float)b[1], c));
#endif
}

__global__ void prep_kernel(const float* __restrict__ W0, const float* __restrict__ W1,
                            const float* __restrict__ W2, const float* __restrict__ hW,
                            _Float16* __restrict__ ws) {
    const int tid = blockIdx.x * blockDim.x + threadIdx.x;
    const int stride = gridDim.x * blockDim.x;
    _Float16* w0f = ws + W0F_OFF / 2;
    _Float16* w1f = ws + W1F_OFF / 2;
    _Float16* w2f = ws + W2F_OFF / 2;
    _Float16* hwt = ws + HWT_OFF / 2;
    for (int i = tid; i < 3 * 4 * 64 * 8; i += stride) {
        int j = i & 7, l = (i >> 3) & 63, fk = i >> 9;   // fk = kk*4+ft
        int kk = fk >> 2, ft = fk & 3;
        int n = ft * 16 + (l & 15);
        int k = kk * 32 + (l >> 4) * 8 + j;
        w0f[i] = (_Float16)(k < INF ? W0[k * HID + n] : 0.0f);
    }
    for (int i = tid; i < 2 * 4 * 64 * 8; i += stride) {
        int j = i & 7, l = (i >> 3) & 63, fk = i >> 9;
        int kk = fk >> 2, ft = fk & 3;
        int n = ft * 16 + (l & 15);
        int k = kk * 32 + (l >> 4) * 8 + j;
        w1f[i] = (_Float16)W1[k * HID + n];
        w2f[i] = (_Float16)W2[k * HID + n];
    }
    for (int i = tid; i < NTASK * OUTF * HID; i += stride) {   // hwT[t][o][k]
        int t = i / (OUTF * HID), rem = i % (OUTF * HID);
        int o = rem / HID, k = rem % HID;
        hwt[i] = (_Float16)hW[(size_t)t * (HID * OUTF) + k * OUTF + o];
    }
}

__global__ __launch_bounds__(NTHR, 6) void mtn_mfma_kernel(
    const float* __restrict__ x,     // [B, 89]
    const int*   __restrict__ task,  // [B]
    const float* __restrict__ b0, const float* __restrict__ b1,
    const float* __restrict__ b2,
    const float* __restrict__ hB,    // [50, 8] fp32
    const _Float16* __restrict__ ws,
    float* __restrict__ out)         // [B, 8]
{
    __shared__ __align__(16) _Float16 hs[4][32][HP];   // 19456 B, wave-private bands

    const int t = threadIdx.x;
    const int w = t >> 6;            // wave 0..3
    const int l = t & 63;
    const int c = l & 15;            // MFMA col (batch) / A row (feat)
    const int g = l >> 4;            // k-group / D row-group
    const int waveRow = blockIdx.x * ROWS + w * 32;   // global row base of this wave

    const _Float16* w0f = ws + W0F_OFF / 2;
    const _Float16* w1f = ws + W1F_OFF / 2;
    const _Float16* w2f = ws + W2F_OFF / 2;
    const _Float16* hwt = ws + HWT_OFF / 2;

    // ---- prefetch task indices (independent loads, issued first)
    const int jr = l >> 3, jo = l & 7;
    int tks[4];
    #pragma unroll
    for (int it = 0; it < 4; ++it)
        tks[it] = task[waveRow + it * 8 + jr];

    // ---- layer-0 B-fragments: direct global->VGPR, convert to f16 in-register
    half8 xf[3][2];
    #pragma unroll
    for (int kk = 0; kk < 3; ++kk)
        #pragma unroll
        for (int bt = 0; bt < 2; ++bt) {
            const size_t batch = (size_t)(waveRow + bt * 16 + c);
            const int k0 = kk * 32 + g * 8;
            half8 hb;
            if (k0 == 88) {                       // kk==2 && g==3: only k=88 valid
                float v = x[batch * INF + 88];
                hb = half8{(_Float16)v, (_Float16)0, (_Float16)0, (_Float16)0,
                           (_Float16)0, (_Float16)0, (_Float16)0, (_Float16)0};
            } else {                              // k0..k0+7 all < 89
                float v[8];
                __builtin_memcpy(v, x + batch * INF + k0, 32);
                #pragma unroll
                for (int i2 = 0; i2 < 8; ++i2) hb[i2] = (_Float16)v[i2];
            }
            xf[kk][bt] = hb;
        }

    // ---- head biases (dependent on task; issued after x loads)
    float hBv[4];
    #pragma unroll
    for (int it = 0; it < 4; ++it)
        hBv[it] = hB[tks[it] * OUTF + jo];

    f32x4 acc[4][2];   // [feat-tile][batch-tile]

    // ================= layer 0: K=96 (89 padded), A frag-ordered =================
    #pragma unroll
    for (int ft = 0; ft < 4; ++ft) {
        f32x4 bv = *(const f32x4*)(b0 + ft * 16 + g * 4);
        acc[ft][0] = bv; acc[ft][1] = bv;
    }
    #pragma unroll
    for (int kk = 0; kk < 3; ++kk)
        #pragma unroll
        for (int ft = 0; ft < 4; ++ft) {
            half8 af = *(const half8*)(w0f + ((kk * 4 + ft) * 64 + l) * 8);  // 16B/lane
            acc[ft][0] = __builtin_amdgcn_mfma_f32_16x16x32_f16(af, xf[kk][0], acc[ft][0], 0, 0, 0);
            acc[ft][1] = __builtin_amdgcn_mfma_f32_16x16x32_f16(af, xf[kk][1], acc[ft][1], 0, 0, 0);
        }
    #pragma unroll
    for (int ft = 0; ft < 4; ++ft)
        #pragma unroll
        for (int bt = 0; bt < 2; ++bt) {
            half4 hv;
            #pragma unroll
            for (int r = 0; r < 4; ++r) hv[r] = (_Float16)fast_tanh(acc[ft][bt][r]);
            *(half4*)&hs[w][bt * 16 + c][ft * 16 + g * 4] = hv;   // 8B store
        }

    // ================= layers 1,2: K=64, B from wave-private LDS band =============
    #pragma unroll
    for (int layer = 0; layer < 2; ++layer) {
        const _Float16* WF  = layer ? w2f : w1f;
        const float*    bia = layer ? b2  : b1;
        #pragma unroll
        for (int ft = 0; ft < 4; ++ft) {
            f32x4 bv = *(const f32x4*)(bia + ft * 16 + g * 4);
            acc[ft][0] = bv; acc[ft][1] = bv;
        }
        #pragma unroll
        for (int kk = 0; kk < 2; ++kk) {
            half8 bf[2];
            #pragma unroll
            for (int bt = 0; bt < 2; ++bt)
                bf[bt] = *(const half8*)&hs[w][bt * 16 + c][kk * 32 + g * 8];  // 16B read
            #pragma unroll
            for (int ft = 0; ft < 4; ++ft) {
                half8 af = *(const half8*)(WF + ((kk * 4 + ft) * 64 + l) * 8);
                acc[ft][0] = __builtin_amdgcn_mfma_f32_16x16x32_f16(af, bf[0], acc[ft][0], 0, 0, 0);
                acc[ft][1] = __builtin_amdgcn_mfma_f32_16x16x32_f16(af, bf[1], acc[ft][1], 0, 0, 0);
            }
        }
        #pragma unroll
        for (int ft = 0; ft < 4; ++ft)
            #pragma unroll
            for (int bt = 0; bt < 2; ++bt) {
                half4 hv;
                #pragma unroll
                for (int r = 0; r < 4; ++r) hv[r] = (_Float16)fast_tanh(acc[ft][bt][r]);
                *(half4*)&hs[w][bt * 16 + c][ft * 16 + g * 4] = hv;
            }
    }

    // ================= head: coalesced weight chunks + transpose-reduce =============
    #pragma unroll
    for (int it = 0; it < 4; ++it) {
        const int r = it * 8 + jr;
        const size_t grow = (size_t)waveRow + r;
        const int tk = tks[it];
        const _Float16* wp = hwt + (size_t)tk * (OUTF * HID) + jo * 8;  // chunk jo
        const half8 hv = *(const half8*)&hs[w][r][jo * 8];              // 1 read/it

        float p[8];
        #pragma unroll
        for (int o = 0; o < 8; ++o) {
            half8 wv = *(const half8*)(wp + o * HID);   // 8 lanes -> 128B contiguous
            float a = 0.0f;
            #pragma unroll
            for (int pp = 0; pp < 4; ++pp) {
                half2v av = {hv[2 * pp], hv[2 * pp + 1]};
                half2v bv = {wv[2 * pp], wv[2 * pp + 1]};
                a = dot2acc(av, bv, a);
            }
            p[o] = a;
        }
        // transpose-reduce across the 8 jo-lanes (static indices only)
        float t0 = p[0] + __shfl_xor(p[0], 1);
        float t1 = p[1] + __shfl_xor(p[1], 1);
        float t2 = p[2] + __shfl_xor(p[2], 1);
        float t3 = p[3] + __shfl_xor(p[3], 1);
        float t4 = p[4] + __shfl_xor(p[4], 1);
        float t5 = p[5] + __shfl_xor(p[5], 1);
        float t6 = p[6] + __shfl_xor(p[6], 1);
        float t7 = p[7] + __shfl_xor(p[7], 1);
        const bool b0s = (jo & 1) != 0;
        float s0 = b0s ? t1 : t0;
        float s1 = b0s ? t3 : t2;
        float s2 = b0s ? t5 : t4;
        float s3 = b0s ? t7 : t6;
        s0 += __shfl_xor(s0, 2);
        s1 += __shfl_xor(s1, 2);
        s2 += __shfl_xor(s2, 2);
        s3 += __shfl_xor(s3, 2);
        const bool b1s = (jo & 2) != 0;
        float u0 = b1s ? s1 : s0;
        float u1 = b1s ? s3 : s2;
        u0 += __shfl_xor(u0, 4);
        u1 += __shfl_xor(u1, 4);
        float res = ((jo & 4) ? u1 : u0) + hBv[it];
        out[grow * OUTF + jo] = res;    // wave stores 64 consecutive dwords
    }
}

extern "C" void kernel_launch(void* const* d_in, const int* in_sizes, int n_in,
                              void* d_out, int out_size, void* d_ws, size_t ws_size,
                              hipStream_t stream) {
    const float* x    = (const float*)d_in[0];
    const int*   task = (const int*)  d_in[1];
    const float* W0   = (const float*)d_in[2];
    const float* b0   = (const float*)d_in[3];
    const float* W1   = (const float*)d_in[4];
    const float* b1   = (const float*)d_in[5];
    const float* W2   = (const float*)d_in[6];
    const float* b2   = (const float*)d_in[7];
    const float* hW   = (const float*)d_in[8];
    const float* hB   = (const float*)d_in[9];
    float* out = (float*)d_out;
    _Float16* ws = (_Float16*)d_ws;

    prep_kernel<<<64, 256, 0, stream>>>(W0, W1, W2, hW, ws);
    mtn_mfma_kernel<<<BN / ROWS, NTHR, 0, stream>>>(x, task, b0, b1, b2, hB, ws, out);
}

// Round 8
// 43.880 us; speedup vs baseline: 1.5160x; 1.5160x over previous
//
#include <hip/hip_runtime.h>
#include <stdint.h>
#include <stddef.h>

// MultiTaskTrunkNetwork: 3x (Linear+Tanh) [89->64->64->64] + per-task head [64->8]
// Round 8: r6 structure at finer block granularity.
//   - 128-thr / 2-wave blocks, 64 rows/block (4096 blocks): 12 blocks/CU resident
//     (vs 6), finer phase diversity, cheaper barriers. Per-wave code identical to r6.
//   - x staged coalesced (float4) -> f16 LDS [64][104]; h in-place; frag-ordered W;
//     coalesced-chunk head + shuffle transpose-reduce.

typedef _Float16 half8 __attribute__((ext_vector_type(8)));
typedef _Float16 half4 __attribute__((ext_vector_type(4)));
typedef _Float16 half2v __attribute__((ext_vector_type(2)));
typedef float    f32x4 __attribute__((ext_vector_type(4)));

constexpr int BN = 262144, INF = 89, HID = 64, OUTF = 8, NTASK = 50;
constexpr int NTHR = 128;     // 2 waves
constexpr int ROWS = 64;      // batch rows per block (32 per wave)
constexpr int XP   = 104;     // LDS row pitch in f16 (208 B; 52-dword stride -> <=2-way banks)
constexpr int XTILE_F  = ROWS * INF;       // 5696 floats per block
constexpr int XTILE_V4 = XTILE_F / 4;      // 1424 float4 = 11*128 + 16

// d_ws layout (bytes) — fragment-ordered weights
constexpr int W0F_OFF = 0;        // [3kk][4ft][64lane][8] f16 = 12288 B (k>=89 zero)
constexpr int W1F_OFF = 12288;    // [2kk][4ft][64lane][8] f16 = 8192 B
constexpr int W2F_OFF = 20480;    // [2kk][4ft][64lane][8] f16 = 8192 B
constexpr int HWT_OFF = 28672;    // [50][8][64] f16 (transposed head weights)

__device__ __forceinline__ float fast_tanh(float v) {
    float e = __expf(2.0f * v);
    return 1.0f - 2.0f * __builtin_amdgcn_rcpf(e + 1.0f);
}

__device__ __forceinline__ float dot2acc(half2v a, half2v b, float c) {
#if __has_builtin(__builtin_amdgcn_fdot2)
    return __builtin_amdgcn_fdot2(a, b, c, false);
#else
    return fmaf((float)a[0], (float)b[0], fmaf((float)a[1], (float)b[1], c));
#endif
}

__global__ void prep_kernel(const float* __restrict__ W0, const float* __restrict__ W1,
                            const float* __restrict__ W2, const float* __restrict__ hW,
                            _Float16* __restrict__ ws) {
    const int tid = blockIdx.x * blockDim.x + threadIdx.x;
    const int stride = gridDim.x * blockDim.x;
    _Float16* w0f = ws + W0F_OFF / 2;
    _Float16* w1f = ws + W1F_OFF / 2;
    _Float16* w2f = ws + W2F_OFF / 2;
    _Float16* hwt = ws + HWT_OFF / 2;
    for (int i = tid; i < 3 * 4 * 64 * 8; i += stride) {
        int j = i & 7, l = (i >> 3) & 63, fk = i >> 9;   // fk = kk*4+ft
        int kk = fk >> 2, ft = fk & 3;
        int n = ft * 16 + (l & 15);
        int k = kk * 32 + (l >> 4) * 8 + j;
        w0f[i] = (_Float16)(k < INF ? W0[k * HID + n] : 0.0f);
    }
    for (int i = tid; i < 2 * 4 * 64 * 8; i += stride) {
        int j = i & 7, l = (i >> 3) & 63, fk = i >> 9;
        int kk = fk >> 2, ft = fk & 3;
        int n = ft * 16 + (l & 15);
        int k = kk * 32 + (l >> 4) * 8 + j;
        w1f[i] = (_Float16)W1[k * HID + n];
        w2f[i] = (_Float16)W2[k * HID + n];
    }
    for (int i = tid; i < NTASK * OUTF * HID; i += stride) {   // hwT[t][o][k]
        int t = i / (OUTF * HID), rem = i % (OUTF * HID);
        int o = rem / HID, k = rem % HID;
        hwt[i] = (_Float16)hW[(size_t)t * (HID * OUTF) + k * OUTF + o];
    }
}

__global__ __launch_bounds__(NTHR, 8) void mtn_mfma_kernel(
    const float* __restrict__ x,     // [B, 89]
    const int*   __restrict__ task,  // [B]
    const float* __restrict__ b0, const float* __restrict__ b1,
    const float* __restrict__ b2,
    const float* __restrict__ hB,    // [50, 8] fp32
    const _Float16* __restrict__ ws,
    float* __restrict__ out)         // [B, 8]
{
    __shared__ __align__(16) _Float16 xh[ROWS * XP];   // 13312 B; x tile, then h in-place

    const int t = threadIdx.x;
    const int w = t >> 6;            // wave 0..1
    const int l = t & 63;
    const int c = l & 15;            // MFMA col (batch) / A row (feat)
    const int g = l >> 4;            // k-group / D row-group
    const int blockRow = blockIdx.x * ROWS;
    const int waveRow  = w * 32;     // this wave's private 32-row LDS band

    const _Float16* w0f = ws + W0F_OFF / 2;
    const _Float16* w1f = ws + W1F_OFF / 2;
    const _Float16* w2f = ws + W2F_OFF / 2;
    const _Float16* hwt = ws + HWT_OFF / 2;

    // ---- prefetch task indices + head biases (issued ~whole kernel early)
    const int jr = l >> 3, jo = l & 7;
    int   tks[4];
    float hBv[4];
    #pragma unroll
    for (int it = 0; it < 4; ++it)
        tks[it] = task[blockRow + waveRow + it * 8 + jr];
    #pragma unroll
    for (int it = 0; it < 4; ++it)
        hBv[it] = hB[tks[it] * OUTF + jo];

    // ---- stage x tile: coalesced float4 flat loads -> f16 LDS [row][k], pitch 104
    {
        const float4* xb = reinterpret_cast<const float4*>(x + (size_t)blockRow * INF);
        #pragma unroll
        for (int i = 0; i < 12; ++i) {
            if (i < 11 || t < XTILE_V4 - 11 * NTHR) {        // 1424 = 11*128 + 16
                float4 v = xb[t + i * NTHR];
                int e = 4 * (t + i * NTHR);
                #pragma unroll
                for (int q = 0; q < 4; ++q) {
                    int ee = e + q;
                    int rr = ee / INF, k = ee - rr * INF;
                    xh[rr * XP + k] = (_Float16)((q == 0) ? v.x : (q == 1) ? v.y
                                                 : (q == 2) ? v.z : v.w);
                }
            }
        }
        if (t < ROWS) {                 // zero-pad k = 89..95
            #pragma unroll
            for (int k = INF; k < 96; ++k) xh[t * XP + k] = (_Float16)0;
        }
    }
    __syncthreads();   // only barrier (2 waves): after this, each wave owns its band

    f32x4 acc[4][2];   // [feat-tile][batch-tile]

    // ================= layer 0: K=96 (89 padded), B from LDS, A frag-ordered =========
    #pragma unroll
    for (int ft = 0; ft < 4; ++ft) {
        f32x4 bv = *(const f32x4*)(b0 + ft * 16 + g * 4);
        acc[ft][0] = bv; acc[ft][1] = bv;
    }
    #pragma unroll
    for (int kk = 0; kk < 3; ++kk) {
        half8 bf[2];
        #pragma unroll
        for (int bt = 0; bt < 2; ++bt)
            bf[bt] = *(const half8*)&xh[(waveRow + bt * 16 + c) * XP + kk * 32 + g * 8];
        #pragma unroll
        for (int ft = 0; ft < 4; ++ft) {
            half8 af = *(const half8*)(w0f + ((kk * 4 + ft) * 64 + l) * 8);  // 16B/lane
            acc[ft][0] = __builtin_amdgcn_mfma_f32_16x16x32_f16(af, bf[0], acc[ft][0], 0, 0, 0);
            acc[ft][1] = __builtin_amdgcn_mfma_f32_16x16x32_f16(af, bf[1], acc[ft][1], 0, 0, 0);
        }
    }
    #pragma unroll
    for (int ft = 0; ft < 4; ++ft)
        #pragma unroll
        for (int bt = 0; bt < 2; ++bt) {
            half4 hv;
            #pragma unroll
            for (int r = 0; r < 4; ++r) hv[r] = (_Float16)fast_tanh(acc[ft][bt][r]);
            *(half4*)&xh[(waveRow + bt * 16 + c) * XP + ft * 16 + g * 4] = hv;
        }

    // ================= layers 1,2: K=64 =================
    #pragma unroll
    for (int layer = 0; layer < 2; ++layer) {
        const _Float16* WF  = layer ? w2f : w1f;
        const float*    bia = layer ? b2  : b1;
        #pragma unroll
        for (int ft = 0; ft < 4; ++ft) {
            f32x4 bv = *(const f32x4*)(bia + ft * 16 + g * 4);
            acc[ft][0] = bv; acc[ft][1] = bv;
        }
        #pragma unroll
        for (int kk = 0; kk < 2; ++kk) {
            half8 bf[2];
            #pragma unroll
            for (int bt = 0; bt < 2; ++bt)
                bf[bt] = *(const half8*)&xh[(waveRow + bt * 16 + c) * XP + kk * 32 + g * 8];
            #pragma unroll
            for (int ft = 0; ft < 4; ++ft) {
                half8 af = *(const half8*)(WF + ((kk * 4 + ft) * 64 + l) * 8);
                acc[ft][0] = __builtin_amdgcn_mfma_f32_16x16x32_f16(af, bf[0], acc[ft][0], 0, 0, 0);
                acc[ft][1] = __builtin_amdgcn_mfma_f32_16x16x32_f16(af, bf[1], acc[ft][1], 0, 0, 0);
            }
        }
        #pragma unroll
        for (int ft = 0; ft < 4; ++ft)
            #pragma unroll
            for (int bt = 0; bt < 2; ++bt) {
                half4 hv;
                #pragma unroll
                for (int r = 0; r < 4; ++r) hv[r] = (_Float16)fast_tanh(acc[ft][bt][r]);
                *(half4*)&xh[(waveRow + bt * 16 + c) * XP + ft * 16 + g * 4] = hv;
            }
    }

    // ================= head: coalesced weight chunks + transpose-reduce =============
    #pragma unroll
    for (int it = 0; it < 4; ++it) {
        const int r = it * 8 + jr;
        const size_t grow = (size_t)blockRow + waveRow + r;
        const int tk = tks[it];
        const _Float16* wp = hwt + (size_t)tk * (OUTF * HID) + jo * 8;  // chunk jo
        const half8 hv = *(const half8*)&xh[(waveRow + r) * XP + jo * 8]; // 1 read/it

        float p[8];
        #pragma unroll
        for (int o = 0; o < 8; ++o) {
            half8 wv = *(const half8*)(wp + o * HID);   // 8 lanes -> 128B contiguous
            float a = 0.0f;
            #pragma unroll
            for (int pp = 0; pp < 4; ++pp) {
                half2v av = {hv[2 * pp], hv[2 * pp + 1]};
                half2v bv = {wv[2 * pp], wv[2 * pp + 1]};
                a = dot2acc(av, bv, a);
            }
            p[o] = a;
        }
        // transpose-reduce across the 8 jo-lanes (static indices only)
        float t0 = p[0] + __shfl_xor(p[0], 1);
        float t1 = p[1] + __shfl_xor(p[1], 1);
        float t2 = p[2] + __shfl_xor(p[2], 1);
        float t3 = p[3] + __shfl_xor(p[3], 1);
        float t4 = p[4] + __shfl_xor(p[4], 1);
        float t5 = p[5] + __shfl_xor(p[5], 1);
        float t6 = p[6] + __shfl_xor(p[6], 1);
        float t7 = p[7] + __shfl_xor(p[7], 1);
        const bool b0s = (jo & 1) != 0;
        float s0 = b0s ? t1 : t0;
        float s1 = b0s ? t3 : t2;
        float s2 = b0s ? t5 : t4;
        float s3 = b0s ? t7 : t6;
        s0 += __shfl_xor(s0, 2);
        s1 += __shfl_xor(s1, 2);
        s2 += __shfl_xor(s2, 2);
        s3 += __shfl_xor(s3, 2);
        const bool b1s = (jo & 2) != 0;
        float u0 = b1s ? s1 : s0;
        float u1 = b1s ? s3 : s2;
        u0 += __shfl_xor(u0, 4);
        u1 += __shfl_xor(u1, 4);
        float res = ((jo & 4) ? u1 : u0) + hBv[it];
        out[grow * OUTF + jo] = res;    // wave stores 64 consecutive dwords
    }
}

extern "C" void kernel_launch(void* const* d_in, const int* in_sizes, int n_in,
                              void* d_out, int out_size, void* d_ws, size_t ws_size,
                              hipStream_t stream) {
    const float* x    = (const float*)d_in[0];
    const int*   task = (const int*)  d_in[1];
    const float* W0   = (const float*)d_in[2];
    const float* b0   = (const float*)d_in[3];
    const float* W1   = (const float*)d_in[4];
    const float* b1   = (const float*)d_in[5];
    const float* W2   = (const float*)d_in[6];
    const float* b2   = (const float*)d_in[7];
    const float* hW   = (const float*)d_in[8];
    const float* hB   = (const float*)d_in[9];
    float* out = (float*)d_out;
    _Float16* ws = (_Float16*)d_ws;

    prep_kernel<<<64, 256, 0, stream>>>(W0, W1, W2, hW, ws);
    mtn_mfma_kernel<<<BN / ROWS, NTHR, 0, stream>>>(x, task, b0, b1, b2, hB, ws, out);
}